// Round 12
// baseline (506.390 us; speedup 1.0000x reference)
//
#include <hip/hip_runtime.h>
#include <math.h>

// ---------------------------------------------------------------------------
// out = (silu(x) @ (W/sigma)^T + b  +  softthr(basis(x) @ Ww^T)) * oscale
// Fused-expansion GEMM: A-operand (wavelet basis) computed on the fly inside
// the GEMM from a precomputed xn = 2.5*tanh(x) plane (f32); silu plane (bf16)
// staged via global_load_lds for the base segment. Merged K = 8192 with kan
// K reordered as (i-chunk major, g minor) so x loads amortize over 7 tiles.
// R8 schedule: 8 waves, 3 LDS buffers, half-K register pipeline, 1 barrier +
// counted vmcnt per tile. softthr in-register at tile 112. No chunking.
// ---------------------------------------------------------------------------

typedef __attribute__((ext_vector_type(4))) float  f32x4;
typedef __attribute__((ext_vector_type(8))) __bf16 bf16x8;
typedef __attribute__((ext_vector_type(8))) unsigned short u16x8;
typedef __attribute__((ext_vector_type(4))) unsigned int u32x4;

#define NROWS 16384
#define INF   1024
#define OUTF  1024
#define GG    7
#define KKAN  7168
#define KTOT  8192

static __device__ __forceinline__ unsigned short f2bf(float f) {
  union { float f; unsigned int u; } v; v.f = f;
  unsigned int r = v.u + 0x7fffu + ((v.u >> 16) & 1u);  // RNE
  return (unsigned short)(r >> 16);
}

// ---------------- sigma (spectral norm) ----------------
__global__ void zero_t(float* __restrict__ t) { t[threadIdx.x] = 0.f; }

__global__ void wtu_acc(const float* __restrict__ W, const float* __restrict__ u,
                        float* __restrict__ t) {
  int tid = threadIdx.x;
  int j4 = tid * 4;
  int i0 = blockIdx.x * 16;
  f32x4 acc = {0.f, 0.f, 0.f, 0.f};
  for (int i = i0; i < i0 + 16; ++i) {
    float ui = u[i];
    f32x4 w4 = *(const f32x4*)(W + (size_t)i * INF + j4);
    acc[0] += w4[0] * ui; acc[1] += w4[1] * ui;
    acc[2] += w4[2] * ui; acc[3] += w4[3] * ui;
  }
  atomicAdd(&t[j4 + 0], acc[0]);
  atomicAdd(&t[j4 + 1], acc[1]);
  atomicAdd(&t[j4 + 2], acc[2]);
  atomicAdd(&t[j4 + 3], acc[3]);
}

__global__ void mv_w_t(const float* __restrict__ W, const float* __restrict__ t,
                       float* __restrict__ s) {
  int i = blockIdx.x;
  int tid = threadIdx.x;
  float p = 0.f;
  for (int j = tid; j < INF; j += 256) p += W[(size_t)i * INF + j] * t[j];
  __shared__ float red[256];
  red[tid] = p; __syncthreads();
  for (int k = 128; k > 0; k >>= 1) { if (tid < k) red[tid] += red[tid + k]; __syncthreads(); }
  if (tid == 0) s[i] = red[0];
}

__global__ void sigma_finish(const float* __restrict__ t, const float* __restrict__ s,
                             const float* __restrict__ st, const float* __restrict__ os,
                             float* __restrict__ scal) {
  __shared__ float r1[256], r2[256];
  int tid = threadIdx.x;
  float p1 = 0.f, p2 = 0.f;
  for (int i = tid; i < 1024; i += 256) { float a = t[i]; p1 += a * a; float b = s[i]; p2 += b * b; }
  r1[tid] = p1; r2[tid] = p2; __syncthreads();
  for (int k = 128; k > 0; k >>= 1) { if (tid < k) { r1[tid] += r1[tid + k]; r2[tid] += r2[tid + k]; } __syncthreads(); }
  if (tid == 0) {
    float nt = sqrtf(r1[0]);
    float ns = sqrtf(r2[0]);
    float nq = ns / (nt + 1e-12f);
    float sigma = nq * nq / (nq + 1e-12f);
    scal[0] = 1.f / sigma;
    scal[1] = log1pf(__expf(st[0]));
    scal[2] = os[0];
  }
}

// ---------------- weight casts into W' [1024][8192] ----------------
__global__ void wsn_cast(const float* __restrict__ w, const float* __restrict__ scal,
                         unsigned short* __restrict__ Wp) {
  float is = scal[0];
  int idx = blockIdx.x * 256 + threadIdx.x;
  int row = idx >> 7, i0 = (idx & 127) << 3;
  const f32x4* p = (const f32x4*)(w + (size_t)row * INF + i0);
  f32x4 a = p[0], b = p[1];
  u16x8 v;
  v[0] = f2bf(a[0] * is); v[1] = f2bf(a[1] * is); v[2] = f2bf(a[2] * is); v[3] = f2bf(a[3] * is);
  v[4] = f2bf(b[0] * is); v[5] = f2bf(b[1] * is); v[6] = f2bf(b[2] * is); v[7] = f2bf(b[3] * is);
  *(u16x8*)(Wp + (size_t)row * KTOT + KKAN + i0) = v;
}

// wavelet_w [o][i*7+g] -> Wp[o][ ((i>>6)*7 + g)*64 + (i&63) ]  (i-chunk major)
__global__ void wkan_cast(const float* __restrict__ w, unsigned short* __restrict__ Wp) {
  __shared__ float row[KKAN];
  int orow = blockIdx.x;
  const float* src = w + (size_t)orow * KKAN;
  for (int c = threadIdx.x * 4; c < KKAN; c += 1024)
    *(f32x4*)&row[c] = *(const f32x4*)&src[c];
  __syncthreads();
  unsigned short* dst = Wp + (size_t)orow * KTOT;
  for (int r = threadIdx.x; r < 896; r += 256) {
    int g = r >> 7, i0 = (r & 127) << 3;
    u16x8 v;
#pragma unroll
    for (int j = 0; j < 8; j++) v[j] = f2bf(row[(i0 + j) * GG + g]);
    *(u16x8*)(dst + ((i0 >> 6) * 7 + g) * 64 + (i0 & 63)) = v;
  }
}

// ---------------- x prep: silu plane (bf16) + xn plane (f32) ----------------
__global__ void xs_prep(const float* __restrict__ x,
                        unsigned short* __restrict__ siluP,
                        float* __restrict__ xnP) {
  int units = NROWS * (INF / 8);
  int stride = gridDim.x * blockDim.x;
  for (int uu = blockIdx.x * blockDim.x + threadIdx.x; uu < units; uu += stride) {
    int row = uu >> 7;
    int i0 = (uu & 127) << 3;
    const f32x4* xp = (const f32x4*)(x + (size_t)row * INF + i0);
    f32x4 xa = xp[0], xb = xp[1];
    float xv[8] = {xa[0], xa[1], xa[2], xa[3], xb[0], xb[1], xb[2], xb[3]};
    u16x8 sb;
    f32x4 na, nb;
#pragma unroll
    for (int j = 0; j < 8; j++) {
      float xx = xv[j];
      float si = xx / (1.f + __expf(-xx));
      sb[j] = f2bf(si);
      float e2 = __expf(2.f * xx);
      float xn = 2.5f * (1.f - 2.f / (e2 + 1.f));
      if (j < 4) na[j] = xn; else nb[j - 4] = xn;
    }
    *(u16x8*)(siluP + (size_t)row * INF + i0) = sb;
    float* np = xnP + (size_t)row * INF + i0;
    *(f32x4*)np = na;
    *(f32x4*)(np + 4) = nb;
  }
}

// ---------------- GEMM machinery ----------------
static __device__ __forceinline__ void gload16(const unsigned short* g, unsigned short* l) {
  __builtin_amdgcn_global_load_lds(
      (const __attribute__((address_space(1))) unsigned int*)g,
      (__attribute__((address_space(3))) unsigned int*)l, 16, 0, 0);
}

static __device__ __forceinline__ float basisf(float x, float is_, float ntri) {
  float xe = fmaf(x, is_, ntri);
  float t2 = xe * xe;
  float ex = __expf(-0.5f * t2);
  return (1.f - t2) * ex;
}

#define SCB   __builtin_amdgcn_sched_barrier(0)
#define SBAR  do { SCB; __builtin_amdgcn_s_barrier(); } while (0)
#define VM(N) asm volatile("s_waitcnt vmcnt(" #N ")" ::: "memory")
#define LG(N) asm volatile("s_waitcnt lgkmcnt(" #N ")" ::: "memory")

// x-chunk load for i-chunk ic: 32 f32 per thread (row = tid>>1, half = tid&1)
#define XLOAD(ic) do { \
    const f32x4* xp_ = (const f32x4*)(xnp + (size_t)(m0 + xrow) * 1024 + (ic) * 64 + 32 * xh); \
    _Pragma("unroll") for (int q = 0; q < 8; ++q) xd[q] = xp_[q]; \
  } while (0)

// B-panel stage for K-tile t2 into buffer db (2 gloads, 128 rows x 64 k)
#define BGLOAD(db, t2) do { \
    const unsigned short* _sb = gB + (size_t)(t2) * 64; \
    unsigned short* _db2 = ldsS + (db) * 24576 + 16384; \
    gload16(_sb, _db2); \
    gload16(_sb + (size_t)64 * KTOT, _db2 + 4096); \
  } while (0)

// compute basis for tile t2 from xd regs, write XOR-swizzled A-tile to buf db
#define CW(db, t2) do { \
    int g2s = (t2) % 7; \
    float is_ = ldsF[g2s]; \
    float ntri = ldsF[7 + g2s]; \
    char* wp_ = (char*)lds + (db) * 49152 + xrow * 128; \
    _Pragma("unroll") for (int q = 0; q < 4; ++q) { \
      unsigned int ov0, ov1, ov2, ov3; \
      { f32x4 xv = xd[2 * q]; \
        float b0 = basisf(xv[0], is_, ntri), b1 = basisf(xv[1], is_, ntri); \
        float b2 = basisf(xv[2], is_, ntri), b3 = basisf(xv[3], is_, ntri); \
        asm("v_cvt_pk_bf16_f32 %0, %1, %2" : "=v"(ov0) : "v"(b0), "v"(b1)); \
        asm("v_cvt_pk_bf16_f32 %0, %1, %2" : "=v"(ov1) : "v"(b2), "v"(b3)); } \
      { f32x4 xv = xd[2 * q + 1]; \
        float b0 = basisf(xv[0], is_, ntri), b1 = basisf(xv[1], is_, ntri); \
        float b2 = basisf(xv[2], is_, ntri), b3 = basisf(xv[3], is_, ntri); \
        asm("v_cvt_pk_bf16_f32 %0, %1, %2" : "=v"(ov2) : "v"(b0), "v"(b1)); \
        asm("v_cvt_pk_bf16_f32 %0, %1, %2" : "=v"(ov3) : "v"(b2), "v"(b3)); } \
      u32x4 w4 = {ov0, ov1, ov2, ov3}; \
      *(u32x4*)(wp_ + (((4 * xh + q) ^ (xrow & 7)) << 4)) = w4; \
    } \
  } while (0)

// base-segment stage (A from silu plane + B), 6 gloads
#define STAGE_BASE(db, t2) do { \
    const unsigned short* _sa = gS + (size_t)((t2) - 112) * 64; \
    const unsigned short* _sb = gB + (size_t)(t2) * 64; \
    unsigned short* _da = ldsS + (db) * 24576; \
    unsigned short* _db2 = _da + 16384; \
    _Pragma("unroll") for (int r = 0; r < 4; ++r) \
      gload16(_sa + (size_t)(r * 64) * 1024, _da + r * 4096); \
    _Pragma("unroll") for (int r = 0; r < 2; ++r) \
      gload16(_sb + (size_t)(r * 64) * KTOT, _db2 + r * 4096); \
  } while (0)

#define RD8(FA, FB, bb, kx) do { \
    _Pragma("unroll") for (int i = 0; i < 4; ++i) \
      FA[i] = *(const bf16x8*)(pA + (bb) * 49152 + i * 2048 + (kx)); \
    _Pragma("unroll") for (int j = 0; j < 4; ++j) \
      FB[j] = *(const bf16x8*)(pB + (bb) * 49152 + j * 2048 + (kx)); \
  } while (0)

#define MM16(FA, FB) do { _Pragma("unroll") for (int i = 0; i < 4; ++i) \
    _Pragma("unroll") for (int j = 0; j < 4; ++j) \
      acc[i][j] = __builtin_amdgcn_mfma_f32_16x16x32_bf16(FA[i], FB[j], acc[i][j], 0, 0, 0); } while (0)

// kan tile: fused A-staging (x held in regs; reload when g2==0)
#define TILE_K(tt, bb, nb, db, W1) do { \
    RD8(fYA, fYB, bb, kx1); \
    SCB; \
    { int t2_ = (tt) + 2; int g2_ = t2_ % 7; int ic_ = t2_ / 7; \
      if (g2_ == 0) { XLOAD(ic_); } \
      SCB; \
      BGLOAD(db, t2_); \
      SCB; \
      __builtin_amdgcn_s_setprio(1); MM16(fXA, fXB); __builtin_amdgcn_s_setprio(0); \
      CW(db, t2_); } \
    LG(0); SCB; \
    W1; \
    SBAR; \
    RD8(fXA, fXB, nb, kx0); SCB; \
    __builtin_amdgcn_s_setprio(1); MM16(fYA, fYB); __builtin_amdgcn_s_setprio(0); \
    LG(0); SCB; \
  } while (0)

// base-style tile: gload staging (or none)
#define TILE_B(tt, bb, nb, db, SS, NR, W1) do { \
    RD8(fYA, fYB, bb, kx1); \
    SCB; \
    if (SS) STAGE_BASE(db, (tt) + 2); \
    SCB; \
    __builtin_amdgcn_s_setprio(1); MM16(fXA, fXB); __builtin_amdgcn_s_setprio(0); \
    LG(0); SCB; \
    W1; \
    SBAR; \
    if (NR) { RD8(fXA, fXB, nb, kx0); SCB; } \
    __builtin_amdgcn_s_setprio(1); MM16(fYA, fYB); __builtin_amdgcn_s_setprio(0); \
    LG(0); SCB; \
  } while (0)

// BM=256 x BN=128, 8 waves (4M x 2N, 64x64), K=8192 merged, softthr at 112
__global__ __launch_bounds__(512, 2) void gemm_k(
    const float* __restrict__ xnp,          // [16384][1024] f32 (2.5*tanh)
    const unsigned short* __restrict__ silu,// [16384][1024] bf16
    const unsigned short* __restrict__ W,   // [1024][8192] bf16
    const float* __restrict__ bias,
    const float* __restrict__ scal,
    const float* __restrict__ trP,          // translation [7]
    const float* __restrict__ scP,          // scale [7]
    float* __restrict__ out) {              // [16384][1024]
  __shared__ unsigned short lds[73760];     // 3x48KB buffers + 64B scalar table
  float* ldsF = (float*)(lds + 73728);

  int bid = blockIdx.x;
  int cpx = gridDim.x >> 3;                 // 512 blocks -> 64
  int swz = (bid & 7) * cpx + (bid >> 3);   // XCD-bijective; n-inner
  int m0 = (swz >> 3) * 256;
  int n0 = (swz & 7) * 128;
  int tid = threadIdx.x;
  int wv = tid >> 6, l = tid & 63;
  int wr = wv >> 1, wc = wv & 1;            // 4M x 2N waves, 64x64 tiles

  float thr = scal[1], osc = scal[2];

  // staging addressing
  int rowq = tid >> 3;
  int swk = ((tid & 7) ^ (rowq & 7)) << 3;
  const unsigned short* gB = W + (size_t)(n0 + rowq) * KTOT + swk;
  const unsigned short* gS = silu + (size_t)(m0 + rowq) * 1024 + swk;
  unsigned short* ldsS = lds + wv * 512;    // wave-uniform dest base

  // fused A-compute addressing
  int xrow = tid >> 1;                      // 0..255
  int xh = tid & 1;

  // frag reads
  int lr = l & 15;
  int kb = (l >> 4) << 4;
  int xr = (l & 7) << 4;
  int kx0 = kb ^ xr;
  int kx1 = (64 | kb) ^ xr;
  const char* pA = (const char*)lds + (wr * 64 + lr) * 128;
  const char* pB = (const char*)lds + 32768 + (wc * 64 + lr) * 128;

  bf16x8 fXA[4], fXB[4], fYA[4], fYB[4];
  f32x4 xd[8];
  f32x4 acc[4][4] = {};

  // scalar table: iss[g], -tr*iss[g]
  if (tid < 7) {
    float s = fabsf(scP[tid]);
    s = s < 0.1f ? 0.1f : s;
    float is_ = 1.0f / s;
    ldsF[tid] = is_;
    ldsF[7 + tid] = -trP[tid] * is_;
  }
  SBAR;

  // prologue: fuse-stage tiles 0 (buf0) and 1 (buf1)
  XLOAD(0);
  SCB;
  BGLOAD(0, 0);
  SCB;
  CW(0, 0);
  BGLOAD(1, 1);
  SCB;
  CW(1, 1);
  LG(0);
  VM(2);                                     // B(0) landed; B(1) in flight
  SBAR;
  RD8(fXA, fXB, 0, kx0);
  LG(0); SCB;

  // kan segment: tiles 0..111 (K reordered: tile t = i_chunk*7 + g)
  for (int t = 0; t < 108; t += 3) {
    TILE_K(t,     0, 1, 2, VM(2));
    TILE_K(t + 1, 1, 2, 0, VM(2));
    TILE_K(t + 2, 2, 0, 1, VM(2));
  }
  TILE_K(108, 0, 1, 2, VM(2));
  TILE_K(109, 1, 2, 0, VM(2));
  TILE_B(110, 2, 0, 1, 1, 1, VM(6));   // stages base tile 112
  TILE_B(111, 0, 1, 2, 1, 1, VM(6));   // stages base tile 113

  // soft-threshold in-register at the kan/base boundary
#pragma unroll
  for (int i = 0; i < 4; ++i)
#pragma unroll
    for (int j = 0; j < 4; ++j)
#pragma unroll
      for (int e = 0; e < 4; ++e) {
        float v = acc[i][j][e];
        float a = fabsf(v) - thr;
        a = a > 0.f ? a : 0.f;
        acc[i][j][e] = v > 0.f ? a : -a;
      }

  // base segment: tiles 112..127
  TILE_B(112, 1, 2, 0, 1, 1, VM(6));
  TILE_B(113, 2, 0, 1, 1, 1, VM(6));
  TILE_B(114, 0, 1, 2, 1, 1, VM(6));
  TILE_B(115, 1, 2, 0, 1, 1, VM(6));
  TILE_B(116, 2, 0, 1, 1, 1, VM(6));
  TILE_B(117, 0, 1, 2, 1, 1, VM(6));
  TILE_B(118, 1, 2, 0, 1, 1, VM(6));
  TILE_B(119, 2, 0, 1, 1, 1, VM(6));
  TILE_B(120, 0, 1, 2, 1, 1, VM(6));
  TILE_B(121, 1, 2, 0, 1, 1, VM(6));
  TILE_B(122, 2, 0, 1, 1, 1, VM(6));
  TILE_B(123, 0, 1, 2, 1, 1, VM(6));
  TILE_B(124, 1, 2, 0, 1, 1, VM(6));  // stages tile 126
  TILE_B(125, 2, 0, 1, 1, 1, VM(6));  // stages tile 127 (last)
  TILE_B(126, 0, 1, 2, 0, 1, VM(0));  // drain -> buf1(=t127) complete
  TILE_B(127, 1, 2, 0, 0, 0, (void)0);

  // epilogue: out = (acc + bias) * oscale
  int rr = m0 + wr * 64 + ((l >> 4) << 2);
  int cc = n0 + wc * 64 + lr;
#pragma unroll
  for (int i = 0; i < 4; ++i)
#pragma unroll
    for (int j = 0; j < 4; ++j) {
      int c = cc + j * 16;
      float bc = bias[c];
#pragma unroll
      for (int e = 0; e < 4; ++e) {
        int r = rr + i * 16 + e;
        out[(size_t)r * OUTF + c] = (acc[i][j][e] + bc) * osc;
      }
    }
}

// ---------------------------------------------------------------------------
extern "C" void kernel_launch(void* const* d_in, const int* in_sizes, int n_in,
                              void* d_out, int out_size, void* d_ws, size_t ws_size,
                              hipStream_t stream) {
  const float* x              = (const float*)d_in[0];
  const float* base_w         = (const float*)d_in[1];
  const float* base_b         = (const float*)d_in[2];
  const float* u              = (const float*)d_in[3];
  const float* translation    = (const float*)d_in[4];
  const float* scale          = (const float*)d_in[5];
  const float* wavelet_w      = (const float*)d_in[6];
  const float* soft_threshold = (const float*)d_in[7];
  const float* output_scale   = (const float*)d_in[8];
  float* out = (float*)d_out;

  char* ws = (char*)d_ws;
  float* t_vec = (float*)ws;                                 // 1024 f32
  float* s_vec = t_vec + 1024;                               // 1024 f32
  float* scal  = s_vec + 1024;                               // 32 f32
  unsigned short* Wp    = (unsigned short*)(ws + 16384);     // 16 MB
  unsigned short* siluP = (unsigned short*)(ws + 16384 + (size_t)KTOT * OUTF * 2);  // 32 MB
  float* xnP = (float*)(ws + 16384 + (size_t)KTOT * OUTF * 2 + (size_t)NROWS * INF * 2);  // 64 MB

  zero_t<<<1, 1024, 0, stream>>>(t_vec);
  wtu_acc<<<64, 256, 0, stream>>>(base_w, u, t_vec);
  mv_w_t<<<1024, 256, 0, stream>>>(base_w, t_vec, s_vec);
  sigma_finish<<<1, 256, 0, stream>>>(t_vec, s_vec, soft_threshold, output_scale, scal);
  wsn_cast<<<512, 256, 0, stream>>>(base_w, scal, Wp);
  wkan_cast<<<1024, 256, 0, stream>>>(wavelet_w, Wp);
  xs_prep<<<2048, 256, 0, stream>>>(x, siluP, xnP);

  gemm_k<<<(NROWS / 256) * 8, 512, 0, stream>>>(xnP, siluP, Wp, base_b, scal,
                                                translation, scale, out);
}